// Round 6
// baseline (266.286 us; speedup 1.0000x reference)
//
#include <hip/hip_runtime.h>

#define IN_F   4096
#define OUT_F  11008
#define BATCH  16
#define BLOCK  256
#define SPLITK 8
#define KCHUNK (IN_F / SPLITK)   // 512 k per block
#define NSTEP  (KCHUNK / 32)     // 16 mfma k-steps

typedef short s16x8 __attribute__((ext_vector_type(8)));   // bf16x8 frag
typedef float f32x4 __attribute__((ext_vector_type(4)));
typedef int   i32x4 __attribute__((ext_vector_type(4)));
typedef unsigned short u16;

__device__ __forceinline__ u16 f32_to_bf16_rne(float f) {
    unsigned u = __float_as_uint(f);
    unsigned r = u + 0x7FFFu + ((u >> 16) & 1u);   // round-nearest-even
    return (u16)(r >> 16);
}
__device__ __forceinline__ float bf16_bits_to_f32(u16 h) {
    return __uint_as_float((unsigned)h << 16);
}

// One dispatch, two jobs:
//  blocks [0, 256):   x[16][4096] f32 -> bf16 hi/lo planes in ws (RNE split)
//  blocks [256, 944): out[b][o] = bias[o]  (so main kernel can atomicAdd)
__global__ __launch_bounds__(BLOCK) void prep_kernel(
    const float* __restrict__ x, const float* __restrict__ bias,
    float* __restrict__ out, u16* __restrict__ xhi, u16* __restrict__ xlo)
{
    const int bid = blockIdx.x;
    const int tid = threadIdx.x;
    if (bid < (BATCH * IN_F) / BLOCK) {
        int i = bid * BLOCK + tid;
        float v  = x[i];
        u16 h    = f32_to_bf16_rne(v);
        float hf = bf16_bits_to_f32(h);
        u16 l    = f32_to_bf16_rne(v - hf);
        xhi[i] = h;
        xlo[i] = l;
    } else {
        int i = (bid - (BATCH * IN_F) / BLOCK) * BLOCK + tid;  // < 176128
        out[i] = bias[i % OUT_F];
    }
}

// Pure streaming MFMA, zero LDS, zero barriers.
// Block (bx, by): 64 outputs [bx*64..), K-chunk [by*512..). Wave wv owns
// o0 = bx*64 + wv*16. mfma_f32_16x16x32_bf16 per k-step (x2 for hi/lo):
//   A[m=lane&15][k=quad*8+j]   <- x planes in ws (m == n index reuse)
//   B[k=quad*8+j][n=lane&15]   <- w row o0+n (exact int8 -> bf16)
//   D[row=quad*4+r][col=n]     -> atomicAdd scale[o]*acc into bias-filled out
// Weights use nontemporal loads so the 256 KB x planes stay L2-resident.
__global__ __launch_bounds__(BLOCK) void qlin_kernel(
    const int*   __restrict__ w,      // [11008, 4096] int8 in int32
    const float* __restrict__ scale,  // [11008]
    const u16*   __restrict__ xhi,    // [16, 4096] bf16 bits
    const u16*   __restrict__ xlo,    // [16, 4096] bf16 bits
    float* __restrict__ out)          // [16, 11008], pre-filled with bias
{
    const int tid  = threadIdx.x;
    const int lane = tid & 63;
    const int wv   = tid >> 6;
    const int n    = lane & 15;       // = B col, = A row (batch)
    const int quad = lane >> 4;
    const int o0   = blockIdx.x * 64 + wv * 16;
    const int kb   = blockIdx.y * KCHUNK;

    const int* __restrict__ wrow = w   + (size_t)(o0 + n) * IN_F + kb + quad * 8;
    const u16* __restrict__ xh   = xhi + n * IN_F + kb + quad * 8;
    const u16* __restrict__ xl   = xlo + n * IN_F + kb + quad * 8;

    i32x4 wa[2], wb[2];
    s16x8 ah[2], al[2];
    wa[0] = __builtin_nontemporal_load((const i32x4*)wrow);
    wb[0] = __builtin_nontemporal_load((const i32x4*)(wrow + 4));
    ah[0] = *(const s16x8*)xh;
    al[0] = *(const s16x8*)xl;

    f32x4 acc = {0.f, 0.f, 0.f, 0.f};

    #pragma unroll
    for (int s = 0; s < NSTEP; ++s) {
        const int cur = s & 1, nxt = cur ^ 1;
        if (s + 1 < NSTEP) {
            wa[nxt] = __builtin_nontemporal_load((const i32x4*)(wrow + (s + 1) * 32));
            wb[nxt] = __builtin_nontemporal_load((const i32x4*)(wrow + (s + 1) * 32 + 4));
            ah[nxt] = *(const s16x8*)(xh + (s + 1) * 32);
            al[nxt] = *(const s16x8*)(xl + (s + 1) * 32);
        }

        // int32 -> f32 -> bf16 truncate: exact for |v| <= 127
        s16x8 bfrag;
        #pragma unroll
        for (int e = 0; e < 4; ++e) {
            bfrag[e]     = (short)(u16)(__float_as_uint((float)wa[cur][e]) >> 16);
            bfrag[4 + e] = (short)(u16)(__float_as_uint((float)wb[cur][e]) >> 16);
        }

        acc = __builtin_amdgcn_mfma_f32_16x16x32_bf16(ah[cur], bfrag, acc, 0, 0, 0);
        acc = __builtin_amdgcn_mfma_f32_16x16x32_bf16(al[cur], bfrag, acc, 0, 0, 0);
    }

    const int   o  = o0 + n;
    const float sc = scale[o];
    #pragma unroll
    for (int r = 0; r < 4; ++r) {
        const int b = quad * 4 + r;
        atomicAdd(&out[(size_t)b * OUT_F + o], acc[r] * sc);
    }
}

extern "C" void kernel_launch(void* const* d_in, const int* in_sizes, int n_in,
                              void* d_out, int out_size, void* d_ws, size_t ws_size,
                              hipStream_t stream) {
    const float* x     = (const float*)d_in[0];
    const int*   w     = (const int*)d_in[1];
    const float* scale = (const float*)d_in[2];
    const float* bias  = (const float*)d_in[3];
    float* out = (float*)d_out;

    u16* xhi = (u16*)d_ws;                                   // 128 KB
    u16* xlo = (u16*)((char*)d_ws + BATCH * IN_F * sizeof(u16)); // +128 KB

    // 256 blocks convert x; 688 blocks init out with bias
    prep_kernel<<<(BATCH * IN_F) / BLOCK + (BATCH * OUT_F) / BLOCK, BLOCK, 0, stream>>>(
        x, bias, out, xhi, xlo);

    dim3 grid(OUT_F / 64, SPLITK);   // 172 x 8 = 1376 blocks
    qlin_kernel<<<grid, dim3(BLOCK), 0, stream>>>(w, scale, xhi, xlo, out);
}